// Round 6
// baseline (449.827 us; speedup 1.0000x reference)
//
#include <hip/hip_runtime.h>
#include <cstdint>
#include <cstddef>

typedef int   v4i __attribute__((ext_vector_type(4)));
typedef float v4f __attribute__((ext_vector_type(4)));

static constexpr int NREP = 16;                 // stats replica count
static constexpr unsigned WAVE_TOTAL = 2048u * 4u;    // k_gemm waves

// ---------------- workspace layout (bytes) ----------------
static constexpr size_t WQ_OFF    = 0;                        // 65536 int8 weights
static constexpr size_t STATS_OFF = 65536;                    // NREP*512 int32 = 32768
static constexpr size_t PART_OFF  = STATS_OFF + NREP*512*4;   // 64 floats
static constexpr size_t CNT_OFF   = PART_OFF + 256;           // 1 uint (padded)
static constexpr size_t AB_OFF    = CNT_OFF + 64;             // 256 float2
static constexpr size_t SBUF_OFF  = 131072 + 2048;            // 16 MiB int8 s-values
static constexpr size_t WS_NEEDED = SBUF_OFF + (size_t)65536 * 256;

// exact round-half-even of p/1792 for |p| <= 13440 (1792 = 7*256)
__device__ __forceinline__ int rhe1792(int p) {
    unsigned u = (unsigned)(p + 17024);      // (p+896) + 9*1792, u in [3584,30464]
    unsigned v = u >> 8;                     // floor(u/256), in [14,119]
    unsigned d = (v * 147u) >> 10;           // floor(v/7), exact for v<=119
    int q = (int)d - 9;                      // round-half-up(p/1792)
    unsigned tie = (unsigned)(((u & 255u) | (v - 7u * d)) == 0u);
    q -= (int)(tie & ((unsigned)q & 1u));    // half-even: ties round to even
    return q;
}

// ---------------- k1: per-block max|w| partials + zero stats/counter ----------------
// No inter-block waiting (deadlock-proof); dispatch boundary publishes partials.
__global__ void k_maxabs(const float* __restrict__ w, float* __restrict__ partials,
                         int* __restrict__ stats, unsigned* __restrict__ counter) {
    __shared__ float wmax[4];
    int idx = blockIdx.x * 256 + threadIdx.x;     // 64 blocks * 256 = 16384 float4
    float4 f = ((const float4*)w)[idx];
    float m = fmaxf(fmaxf(fabsf(f.x), fabsf(f.y)), fmaxf(fabsf(f.z), fabsf(f.w)));
    #pragma unroll
    for (int s = 32; s > 0; s >>= 1) m = fmaxf(m, __shfl_xor(m, s, 64));
    if ((threadIdx.x & 63) == 0) wmax[threadIdx.x >> 6] = m;
    if (idx < NREP * 512) stats[idx] = 0;         // zero replicas
    if (idx == 0) *counter = 0u;                  // zero gemm wave-counter
    __syncthreads();
    if (threadIdx.x == 0)
        partials[blockIdx.x] = fmaxf(fmaxf(wmax[0], wmax[1]), fmaxf(wmax[2], wmax[3]));
}

// wave-redundant reduce of the 64 partials (L2-hot) -> global max|w|
__device__ __forceinline__ float reduce_partials(const float* __restrict__ partials, int tid) {
    float p = partials[tid & 63];
    #pragma unroll
    for (int s = 32; s > 0; s >>= 1) p = fmaxf(p, __shfl_xor(p, s, 64));
    return p;
}

// ---------------- k2: quantize weights to int8 ----------------
__global__ void k_wquant(const float* __restrict__ w, const float* __restrict__ partials,
                         signed char* __restrict__ wq) {
    int idx = blockIdx.x * 256 + threadIdx.x;
    float scale = reduce_partials(partials, threadIdx.x) / 7.0f;  // scale_w (f32 div, as ref)
    float4 f = ((const float4*)w)[idx];
    int q0 = (int)rintf(fminf(fmaxf(f.x / scale, -7.f), 7.f));
    int q1 = (int)rintf(fminf(fmaxf(f.y / scale, -7.f), 7.f));
    int q2 = (int)rintf(fminf(fmaxf(f.z / scale, -7.f), 7.f));
    int q3 = (int)rintf(fminf(fmaxf(f.w / scale, -7.f), 7.f));
    ((int*)wq)[idx] = (q0 & 255) | ((q1 & 255) << 8) | ((q2 & 255) << 16) | ((q3 & 255) << 24);
}

// ---------------- k3: int8 MFMA GEMM + psum quant + stats + AB tail ----------------
// 2048 blocks x 256 threads (4 waves), 32 batch rows/block. __launch_bounds__(256,4):
// 4 blocks/CU -> 1024 co-resident = exactly 2 full rounds (no straggler round),
// 16 waves/CU latency hiding. Last wave (device counter, no spin) computes AB.
template <typename ST>
__global__ __launch_bounds__(256, 4) void k_gemm(
    const float* __restrict__ x, const signed char* __restrict__ wq,
    ST* __restrict__ sbuf, int* __restrict__ stats,
    const float* __restrict__ partials, unsigned* __restrict__ counter,
    const float* __restrict__ gamma, const float* __restrict__ beta,
    float2* __restrict__ AB)
{
    __shared__ __align__(16) signed char ldsx[32 * 272];   // 32 rows x 256 k (+16B pad/row)
    const int tid  = threadIdx.x;
    const int lane = tid & 63;
    const int wv   = tid >> 6;
    const int obase = wv * 64;
    const int lr = lane & 15, quad = lane >> 4;
    const size_t rb0 = (size_t)blockIdx.x * 32;

    // ---- issue all 32-row x loads (coalesced 4KB/inst; NT keeps L2 for sbuf/wq) ----
    v4f f[8];
    const v4f* xb = (const v4f*)(x + rb0 * 256);
    #pragma unroll
    for (int j = 0; j < 8; ++j)
        f[j] = __builtin_nontemporal_load(&xb[j * 256 + tid]);

    // ---- weight fragments (L2-hot): B-operand layout n=lane&15, k=quad*16+i ----
    v4i wf[4][4];
    #pragma unroll
    for (int ot = 0; ot < 4; ++ot)
        #pragma unroll
        for (int kt = 0; kt < 4; ++kt)
            wf[ot][kt] = *(const v4i*)(wq + (size_t)(obase + ot * 16 + lr) * 256 + kt * 64 + quad * 16);

    // ---- quantize acts to int8 -> LDS ----
    #pragma unroll
    for (int j = 0; j < 8; ++j) {
        int idx = j * 256 + tid;            // float4 flat index (0..2047)
        int row = idx >> 6, c = idx & 63;
        int b0 = (int)rintf(fminf(fmaxf(f[j][0], 0.f), 1.f) * 15.f);
        int b1 = (int)rintf(fminf(fmaxf(f[j][1], 0.f), 1.f) * 15.f);
        int b2 = (int)rintf(fminf(fmaxf(f[j][2], 0.f), 1.f) * 15.f);
        int b3 = (int)rintf(fminf(fmaxf(f[j][3], 0.f), 1.f) * 15.f);
        *(int*)(ldsx + row * 272 + c * 4) = b0 | (b1 << 8) | (b2 << 16) | (b3 << 24);
    }
    __syncthreads();   // the ONLY barrier

    int ssum[4] = {0, 0, 0, 0};
    int ssq[4]  = {0, 0, 0, 0};

    #pragma unroll
    for (int t = 0; t < 2; ++t) {
        v4i a[4];
        #pragma unroll
        for (int kt = 0; kt < 4; ++kt)
            a[kt] = *(const v4i*)(ldsx + (t * 16 + lr) * 272 + kt * 64 + quad * 16);
        const size_t rowbase = rb0 + (size_t)t * 16;
        #pragma unroll
        for (int ot = 0; ot < 4; ++ot) {
            // acc0 -> q0 first, then acc1: keeps peak live VGPRs under the 128 cap
            v4i acc = {0, 0, 0, 0};
            acc = __builtin_amdgcn_mfma_i32_16x16x64_i8(a[0], wf[ot][0], acc, 0, 0, 0);
            acc = __builtin_amdgcn_mfma_i32_16x16x64_i8(a[1], wf[ot][1], acc, 0, 0, 0);
            int q0[4];
            #pragma unroll
            for (int e = 0; e < 4; ++e) q0[e] = rhe1792(acc[e]);
            acc = v4i{0, 0, 0, 0};
            acc = __builtin_amdgcn_mfma_i32_16x16x64_i8(a[2], wf[ot][2], acc, 0, 0, 0);
            acc = __builtin_amdgcn_mfma_i32_16x16x64_i8(a[3], wf[ot][3], acc, 0, 0, 0);
            ST* sp = sbuf + (rowbase + quad * 4) * 256 + obase + ot * 16 + lr;
            #pragma unroll
            for (int e = 0; e < 4; ++e) {
                int s = q0[e] + rhe1792(acc[e]);   // exact, in [-16,16]
                ssum[ot] += s;
                ssq[ot]  += s * s;
                sp[(size_t)e * 256] = (ST)s;
            }
        }
    }
    // ---- per-channel stats into replica buffer ----
    int* st = stats + (blockIdx.x & (NREP - 1)) * 512;
    #pragma unroll
    for (int ot = 0; ot < 4; ++ot) {
        int v = ssum[ot], u = ssq[ot];
        v += __shfl_xor(v, 16, 64); v += __shfl_xor(v, 32, 64);
        u += __shfl_xor(u, 16, 64); u += __shfl_xor(u, 32, 64);
        if (quad == 0) {
            atomicAdd(&st[obase + ot * 16 + lr], v);
            atomicAdd(&st[256 + obase + ot * 16 + lr], u);
        }
    }
    // ---- last-wave AB computation (replaces the k_stats kernel; no spin) ----
    // ACQ_REL fetch_add: release orders THIS wave's stats atomics before the count;
    // the final wave's acquire synchronizes-with all prior releases.
    unsigned r = 0;
    if (lane == 0)
        r = __hip_atomic_fetch_add(counter, 1u, __ATOMIC_ACQ_REL, __HIP_MEMORY_SCOPE_AGENT);
    int isLast = __shfl((lane == 0 && r == WAVE_TOTAL - 1) ? 1 : 0, 0, 64);
    if (isLast) {
        // relaxed agent-scope atomic loads: coherence-point reads, immune to stale XCD L2
        float pm = __uint_as_float(__hip_atomic_load((const unsigned*)&partials[lane],
                                   __ATOMIC_RELAXED, __HIP_MEMORY_SCOPE_AGENT));
        #pragma unroll
        for (int s = 32; s > 0; s >>= 1) pm = fmaxf(pm, __shfl_xor(pm, s, 64));
        float scale_w = pm / 7.0f;
        float tt = scale_w / 15.0f;              // ref: scale_w / qmax_a in f32
        double Cs = 1792.0 * (double)tt;
        const double N = 65536.0;
        #pragma unroll
        for (int c = 0; c < 4; ++c) {
            int o = lane + 64 * c;
            int s = 0, q = 0;
            #pragma unroll
            for (int rr = 0; rr < NREP; ++rr) {
                s += __hip_atomic_load(&stats[rr * 512 + o],
                                       __ATOMIC_RELAXED, __HIP_MEMORY_SCOPE_AGENT);
                q += __hip_atomic_load(&stats[rr * 512 + 256 + o],
                                       __ATOMIC_RELAXED, __HIP_MEMORY_SCOPE_AGENT);
            }
            double mean_s = (double)s / N;
            double var_s  = (double)q / N - mean_s * mean_s;
            double inv    = 1.0 / sqrt(Cs * Cs * var_s + 1e-5);
            double A = Cs * inv * (double)gamma[o];
            double B = (double)beta[o] - Cs * mean_s * inv * (double)gamma[o];
            AB[o] = make_float2((float)A, (float)B);   // plain store; next kernel reads
        }
    }
}

// ---------------- k4: epilogue — BN affine + clipped-ReLU quant ----------------
// 4096 blocks x 256 threads; thread t handles 4-elem groups at flat int-index
// blk*1024 + j*256 + t: loads AND stores fully coalesced, no LDS.
template <typename LT>
__global__ __launch_bounds__(256) void k_out(const LT* sbuf, const float2* __restrict__ AB,
                                             float* out)
{
    const int tid = threadIdx.x;
    const int o0 = (tid * 4) & 255;
    const float4 ab01 = *(const float4*)((const float*)AB + 2 * o0);      // A0,B0,A1,B1
    const float4 ab23 = *(const float4*)((const float*)AB + 2 * o0 + 4);  // A2,B2,A3,B3
    const size_t base = (size_t)blockIdx.x * 1024 + tid;   // 4-element-group index
    #pragma unroll
    for (int j = 0; j < 4; ++j) {
        const size_t F4 = base + (size_t)j * 256;
        float v0, v1, v2, v3;
        if constexpr (sizeof(LT) == 1) {
            int sv = ((const int*)sbuf)[F4];
            v0 = (float)((sv << 24) >> 24);
            v1 = (float)((sv << 16) >> 24);
            v2 = (float)((sv << 8) >> 24);
            v3 = (float)(sv >> 24);
        } else {
            v4f fl = ((const v4f*)sbuf)[F4];
            v0 = fl[0]; v1 = fl[1]; v2 = fl[2]; v3 = fl[3];
        }
        float y0 = rintf(fminf(fmaxf(v0 * ab01.x + ab01.y, 0.f), 1.f) * 15.f);
        float y1 = rintf(fminf(fmaxf(v1 * ab01.z + ab01.w, 0.f), 1.f) * 15.f);
        float y2 = rintf(fminf(fmaxf(v2 * ab23.x + ab23.y, 0.f), 1.f) * 15.f);
        float y3 = rintf(fminf(fmaxf(v3 * ab23.z + ab23.w, 0.f), 1.f) * 15.f);
        const float inv15 = 0.066666666666666666f;
        v4f o = { y0 * inv15, y1 * inv15, y2 * inv15, y3 * inv15 };
        __builtin_nontemporal_store(o, (v4f*)out + F4);   // out never re-read
    }
}

// ---------------- launch ----------------
extern "C" void kernel_launch(void* const* d_in, const int* in_sizes, int n_in,
                              void* d_out, int out_size, void* d_ws, size_t ws_size,
                              hipStream_t stream)
{
    const float* x     = (const float*)d_in[0];
    const float* w     = (const float*)d_in[1];
    const float* gamma = (const float*)d_in[2];
    const float* beta  = (const float*)d_in[3];
    float* out = (float*)d_out;
    char* ws = (char*)d_ws;

    signed char* wq       = (signed char*)(ws + WQ_OFF);
    int*         stats    = (int*)(ws + STATS_OFF);
    float*       partials = (float*)(ws + PART_OFF);
    unsigned*    counter  = (unsigned*)(ws + CNT_OFF);
    float2*      AB       = (float2*)(ws + AB_OFF);

    k_maxabs<<<dim3(64), dim3(256), 0, stream>>>(w, partials, stats, counter);
    k_wquant<<<dim3(64), dim3(256), 0, stream>>>(w, partials, wq);

    if (ws_size >= WS_NEEDED) {
        signed char* sbuf = (signed char*)(ws + SBUF_OFF);
        k_gemm<signed char><<<dim3(2048), dim3(256), 0, stream>>>(
            x, wq, sbuf, stats, partials, counter, gamma, beta, AB);
        k_out<signed char><<<dim3(4096), dim3(256), 0, stream>>>(sbuf, AB, out);
    } else {
        // fallback: stage s as fp32 in d_out, finish in place (same-thread indices)
        k_gemm<float><<<dim3(2048), dim3(256), 0, stream>>>(
            x, wq, out, stats, partials, counter, gamma, beta, AB);
        k_out<float><<<dim3(4096), dim3(256), 0, stream>>>(out, AB, out);
    }
}

// Round 7
// 146.794 us; speedup vs baseline: 3.0643x; 3.0643x over previous
//
#include <hip/hip_runtime.h>
#include <cstdint>
#include <cstddef>

typedef int   v4i __attribute__((ext_vector_type(4)));
typedef float v4f __attribute__((ext_vector_type(4)));

static constexpr int NREP = 16;   // stats replica count (atomic contention spreading)

// ---------------- workspace layout (bytes) ----------------
static constexpr size_t WQ_OFF    = 0;                        // 65536 int8 weights
static constexpr size_t STATS_OFF = 65536;                    // NREP*512 int32 = 32768
static constexpr size_t PART_OFF  = STATS_OFF + NREP*512*4;   // 64 floats
static constexpr size_t AB_OFF    = PART_OFF + 256;           // 256 float2
static constexpr size_t SBUF_OFF  = 131072 + 2048;            // 16 MiB int8 s-values
static constexpr size_t WS_NEEDED = SBUF_OFF + (size_t)65536 * 256;

// exact round-half-even of p/1792 for |p| <= 13440 (1792 = 7*256)
__device__ __forceinline__ int rhe1792(int p) {
    unsigned u = (unsigned)(p + 17024);      // (p+896) + 9*1792, u in [3584,30464]
    unsigned v = u >> 8;                     // floor(u/256), in [14,119]
    unsigned d = (v * 147u) >> 10;           // floor(v/7), exact for v<=119
    int q = (int)d - 9;                      // round-half-up(p/1792)
    unsigned tie = (unsigned)(((u & 255u) | (v - 7u * d)) == 0u);
    q -= (int)(tie & ((unsigned)q & 1u));    // half-even: ties round to even
    return q;
}

// ---------------- k1: per-block max|w| partials + zero stats ----------------
// No inter-block waiting; dispatch boundary publishes partials.
__global__ void k_maxabs(const float* __restrict__ w, float* __restrict__ partials,
                         int* __restrict__ stats) {
    __shared__ float wmax[4];
    int idx = blockIdx.x * 256 + threadIdx.x;     // 64 blocks * 256 = 16384 float4
    float4 f = ((const float4*)w)[idx];
    float m = fmaxf(fmaxf(fabsf(f.x), fabsf(f.y)), fmaxf(fabsf(f.z), fabsf(f.w)));
    #pragma unroll
    for (int s = 32; s > 0; s >>= 1) m = fmaxf(m, __shfl_xor(m, s, 64));
    if ((threadIdx.x & 63) == 0) wmax[threadIdx.x >> 6] = m;
    if (idx < NREP * 512) stats[idx] = 0;         // zero replicas
    __syncthreads();
    if (threadIdx.x == 0)
        partials[blockIdx.x] = fmaxf(fmaxf(wmax[0], wmax[1]), fmaxf(wmax[2], wmax[3]));
}

// wave-redundant reduce of the 64 partials (L2-hot) -> global max|w|
__device__ __forceinline__ float reduce_partials(const float* __restrict__ partials, int tid) {
    float p = partials[tid & 63];
    #pragma unroll
    for (int s = 32; s > 0; s >>= 1) p = fmaxf(p, __shfl_xor(p, s, 64));
    return p;
}

// ---------------- k2: quantize weights to int8 ----------------
__global__ void k_wquant(const float* __restrict__ w, const float* __restrict__ partials,
                         signed char* __restrict__ wq) {
    int idx = blockIdx.x * 256 + threadIdx.x;
    float scale = reduce_partials(partials, threadIdx.x) / 7.0f;  // scale_w (f32 div, as ref)
    float4 f = ((const float4*)w)[idx];
    int q0 = (int)rintf(fminf(fmaxf(f.x / scale, -7.f), 7.f));
    int q1 = (int)rintf(fminf(fmaxf(f.y / scale, -7.f), 7.f));
    int q2 = (int)rintf(fminf(fmaxf(f.z / scale, -7.f), 7.f));
    int q3 = (int)rintf(fminf(fmaxf(f.w / scale, -7.f), 7.f));
    ((int*)wq)[idx] = (q0 & 255) | ((q1 & 255) << 8) | ((q2 & 255) << 16) | ((q3 & 255) << 24);
}

// ---------------- k3: int8 MFMA GEMM + per-tile psum quant + stats ----------------
// 2048 blocks x 256 threads (4 waves), 32 batch rows/block. __launch_bounds__(256,3):
// the R2-R4-proven register regime (~170 cap) — pressure here is LOWER than R4
// (f[8]=32 regs vs f[16]=64), so wf[4][4] stays resident. 2048 blocks at 768
// co-resident = rounds 768+768+512 (~89% width vs R4's 67%).
// NO fences / NO tail reduction in this kernel — stats via plain relaxed atomicAdd;
// the dispatch boundary orders everything for k_stats.
template <typename ST>
__global__ __launch_bounds__(256, 3) void k_gemm(
    const float* __restrict__ x, const signed char* __restrict__ wq,
    ST* __restrict__ sbuf, int* __restrict__ stats)
{
    __shared__ __align__(16) signed char ldsx[32 * 272];   // 32 rows x 256 k (+16B pad/row)
    const int tid  = threadIdx.x;
    const int lane = tid & 63;
    const int wv   = tid >> 6;
    const int obase = wv * 64;
    const int lr = lane & 15, quad = lane >> 4;
    const size_t rb0 = (size_t)blockIdx.x * 32;

    // ---- issue all 32-row x loads (coalesced 4KB/inst; NT keeps L2 for sbuf/wq) ----
    v4f f[8];
    const v4f* xb = (const v4f*)(x + rb0 * 256);
    #pragma unroll
    for (int j = 0; j < 8; ++j)
        f[j] = __builtin_nontemporal_load(&xb[j * 256 + tid]);

    // ---- weight fragments (L2-hot): B-operand layout n=lane&15, k=quad*16+i ----
    v4i wf[4][4];
    #pragma unroll
    for (int ot = 0; ot < 4; ++ot)
        #pragma unroll
        for (int kt = 0; kt < 4; ++kt)
            wf[ot][kt] = *(const v4i*)(wq + (size_t)(obase + ot * 16 + lr) * 256 + kt * 64 + quad * 16);

    // ---- quantize acts to int8 -> LDS ----
    #pragma unroll
    for (int j = 0; j < 8; ++j) {
        int idx = j * 256 + tid;            // float4 flat index (0..2047)
        int row = idx >> 6, c = idx & 63;
        int b0 = (int)rintf(fminf(fmaxf(f[j][0], 0.f), 1.f) * 15.f);
        int b1 = (int)rintf(fminf(fmaxf(f[j][1], 0.f), 1.f) * 15.f);
        int b2 = (int)rintf(fminf(fmaxf(f[j][2], 0.f), 1.f) * 15.f);
        int b3 = (int)rintf(fminf(fmaxf(f[j][3], 0.f), 1.f) * 15.f);
        *(int*)(ldsx + row * 272 + c * 4) = b0 | (b1 << 8) | (b2 << 16) | (b3 << 24);
    }
    __syncthreads();   // the ONLY barrier

    int ssum[4] = {0, 0, 0, 0};
    int ssq[4]  = {0, 0, 0, 0};

    #pragma unroll
    for (int t = 0; t < 2; ++t) {
        v4i a[4];
        #pragma unroll
        for (int kt = 0; kt < 4; ++kt)
            a[kt] = *(const v4i*)(ldsx + (t * 16 + lr) * 272 + kt * 64 + quad * 16);
        const size_t rowbase = rb0 + (size_t)t * 16;
        #pragma unroll
        for (int ot = 0; ot < 4; ++ot) {
            v4i acc0 = {0, 0, 0, 0}, acc1 = {0, 0, 0, 0};
            acc0 = __builtin_amdgcn_mfma_i32_16x16x64_i8(a[0], wf[ot][0], acc0, 0, 0, 0);
            acc0 = __builtin_amdgcn_mfma_i32_16x16x64_i8(a[1], wf[ot][1], acc0, 0, 0, 0);
            acc1 = __builtin_amdgcn_mfma_i32_16x16x64_i8(a[2], wf[ot][2], acc1, 0, 0, 0);
            acc1 = __builtin_amdgcn_mfma_i32_16x16x64_i8(a[3], wf[ot][3], acc1, 0, 0, 0);
            ST* sp = sbuf + (rowbase + quad * 4) * 256 + obase + ot * 16 + lr;
            #pragma unroll
            for (int e = 0; e < 4; ++e) {
                int s = rhe1792(acc0[e]) + rhe1792(acc1[e]);   // exact, in [-16,16]
                ssum[ot] += s;
                ssq[ot]  += s * s;
                sp[(size_t)e * 256] = (ST)s;
            }
        }
    }
    // ---- per-channel stats into replica buffer (plain relaxed device atomics) ----
    int* st = stats + (blockIdx.x & (NREP - 1)) * 512;
    #pragma unroll
    for (int ot = 0; ot < 4; ++ot) {
        int v = ssum[ot], u = ssq[ot];
        v += __shfl_xor(v, 16, 64); v += __shfl_xor(v, 32, 64);
        u += __shfl_xor(u, 16, 64); u += __shfl_xor(u, 32, 64);
        if (quad == 0) {
            atomicAdd(&st[obase + ot * 16 + lr], v);
            atomicAdd(&st[256 + obase + ot * 16 + lr], u);
        }
    }
}

// ---------------- k4: per-channel BN affine from exact integer stats ----------------
__global__ void k_stats(const int* __restrict__ stats, const float* __restrict__ partials,
                        const float* __restrict__ gamma, const float* __restrict__ beta,
                        float2* __restrict__ AB)
{
    int o = threadIdx.x;
    int s = 0, q = 0;
    #pragma unroll
    for (int rr = 0; rr < NREP; ++rr) {
        s += stats[rr * 512 + o];
        q += stats[rr * 512 + 256 + o];
    }
    float scale_w = reduce_partials(partials, o) / 7.0f;
    float t = scale_w / 15.0f;                 // ref: scale_w / qmax_a in f32
    double Cs = 1792.0 * (double)t;            // acc = s * Cs
    const double N = 65536.0;
    double mean_s = (double)s / N;
    double var_s  = (double)q / N - mean_s * mean_s;
    double var    = Cs * Cs * var_s;
    double inv    = 1.0 / sqrt(var + 1e-5);
    double A = Cs * inv * (double)gamma[o];
    double B = (double)beta[o] - Cs * mean_s * inv * (double)gamma[o];
    AB[o] = make_float2((float)A, (float)B);
}

// ---------------- k5: epilogue — BN affine + clipped-ReLU quant ----------------
// 4096 blocks x 256 threads; thread t handles 4-elem groups at flat int-index
// blk*1024 + j*256 + t: loads AND stores fully coalesced, no LDS.
template <typename LT>
__global__ __launch_bounds__(256) void k_out(const LT* sbuf, const float2* __restrict__ AB,
                                             float* out)
{
    const int tid = threadIdx.x;
    const int o0 = (tid * 4) & 255;
    const float4 ab01 = *(const float4*)((const float*)AB + 2 * o0);      // A0,B0,A1,B1
    const float4 ab23 = *(const float4*)((const float*)AB + 2 * o0 + 4);  // A2,B2,A3,B3
    const size_t base = (size_t)blockIdx.x * 1024 + tid;   // 4-element-group index
    #pragma unroll
    for (int j = 0; j < 4; ++j) {
        const size_t F4 = base + (size_t)j * 256;
        float v0, v1, v2, v3;
        if constexpr (sizeof(LT) == 1) {
            int sv = ((const int*)sbuf)[F4];
            v0 = (float)((sv << 24) >> 24);
            v1 = (float)((sv << 16) >> 24);
            v2 = (float)((sv << 8) >> 24);
            v3 = (float)(sv >> 24);
        } else {
            v4f fl = ((const v4f*)sbuf)[F4];
            v0 = fl[0]; v1 = fl[1]; v2 = fl[2]; v3 = fl[3];
        }
        float y0 = rintf(fminf(fmaxf(v0 * ab01.x + ab01.y, 0.f), 1.f) * 15.f);
        float y1 = rintf(fminf(fmaxf(v1 * ab01.z + ab01.w, 0.f), 1.f) * 15.f);
        float y2 = rintf(fminf(fmaxf(v2 * ab23.x + ab23.y, 0.f), 1.f) * 15.f);
        float y3 = rintf(fminf(fmaxf(v3 * ab23.z + ab23.w, 0.f), 1.f) * 15.f);
        const float inv15 = 0.066666666666666666f;
        v4f o = { y0 * inv15, y1 * inv15, y2 * inv15, y3 * inv15 };
        __builtin_nontemporal_store(o, (v4f*)out + F4);   // out never re-read
    }
}

// ---------------- launch ----------------
extern "C" void kernel_launch(void* const* d_in, const int* in_sizes, int n_in,
                              void* d_out, int out_size, void* d_ws, size_t ws_size,
                              hipStream_t stream)
{
    const float* x     = (const float*)d_in[0];
    const float* w     = (const float*)d_in[1];
    const float* gamma = (const float*)d_in[2];
    const float* beta  = (const float*)d_in[3];
    float* out = (float*)d_out;
    char* ws = (char*)d_ws;

    signed char* wq       = (signed char*)(ws + WQ_OFF);
    int*         stats    = (int*)(ws + STATS_OFF);
    float*       partials = (float*)(ws + PART_OFF);
    float2*      AB       = (float2*)(ws + AB_OFF);

    k_maxabs<<<dim3(64), dim3(256), 0, stream>>>(w, partials, stats);
    k_wquant<<<dim3(64), dim3(256), 0, stream>>>(w, partials, wq);

    if (ws_size >= WS_NEEDED) {
        signed char* sbuf = (signed char*)(ws + SBUF_OFF);
        k_gemm<signed char><<<dim3(2048), dim3(256), 0, stream>>>(x, wq, sbuf, stats);
        k_stats<<<dim3(1), dim3(256), 0, stream>>>(stats, partials, gamma, beta, AB);
        k_out<signed char><<<dim3(4096), dim3(256), 0, stream>>>(sbuf, AB, out);
    } else {
        // fallback: stage s as fp32 in d_out, finish in place (same-thread indices)
        k_gemm<float><<<dim3(2048), dim3(256), 0, stream>>>(x, wq, out, stats);
        k_stats<<<dim3(1), dim3(256), 0, stream>>>(stats, partials, gamma, beta, AB);
        k_out<float><<<dim3(4096), dim3(256), 0, stream>>>(out, AB, out);
    }
}

// Round 9
// 141.335 us; speedup vs baseline: 3.1827x; 1.0386x over previous
//
#include <hip/hip_runtime.h>
#include <cstdint>
#include <cstddef>

typedef int   v4i __attribute__((ext_vector_type(4)));
typedef float v4f __attribute__((ext_vector_type(4)));

static constexpr int NREP = 16;   // stats replica count (atomic contention spreading)

// ---------------- workspace layout (bytes) ----------------
static constexpr size_t WQ_OFF    = 0;                        // 65536 int8 weights
static constexpr size_t STATS_OFF = 65536;                    // NREP*512 int32 = 32768
static constexpr size_t PART_OFF  = STATS_OFF + NREP*512*4;   // 64 floats
static constexpr size_t AB_OFF    = PART_OFF + 256;           // 256 float2
static constexpr size_t SBUF_OFF  = 131072 + 2048;            // 16 MiB int8 s-values
static constexpr size_t WS_NEEDED = SBUF_OFF + (size_t)65536 * 256;

// exact round-half-even of p/1792 for |p| <= 13440 (1792 = 7*256)
__device__ __forceinline__ int rhe1792(int p) {
    unsigned u = (unsigned)(p + 17024);      // (p+896) + 9*1792, u in [3584,30464]
    unsigned v = u >> 8;                     // floor(u/256), in [14,119]
    unsigned d = (v * 147u) >> 10;           // floor(v/7), exact for v<=119
    int q = (int)d - 9;                      // round-half-up(p/1792)
    unsigned tie = (unsigned)(((u & 255u) | (v - 7u * d)) == 0u);
    q -= (int)(tie & ((unsigned)q & 1u));    // half-even: ties round to even
    return q;
}

// ---------------- k1: per-block max|w| partials + zero stats ----------------
__global__ void k_maxabs(const float* __restrict__ w, float* __restrict__ partials,
                         int* __restrict__ stats) {
    __shared__ float wmax[4];
    int idx = blockIdx.x * 256 + threadIdx.x;     // 64 blocks * 256 = 16384 float4
    float4 f = ((const float4*)w)[idx];
    float m = fmaxf(fmaxf(fabsf(f.x), fabsf(f.y)), fmaxf(fabsf(f.z), fabsf(f.w)));
    #pragma unroll
    for (int s = 32; s > 0; s >>= 1) m = fmaxf(m, __shfl_xor(m, s, 64));
    if ((threadIdx.x & 63) == 0) wmax[threadIdx.x >> 6] = m;
    if (idx < NREP * 512) stats[idx] = 0;         // zero replicas
    __syncthreads();
    if (threadIdx.x == 0)
        partials[blockIdx.x] = fmaxf(fmaxf(wmax[0], wmax[1]), fmaxf(wmax[2], wmax[3]));
}

// wave-redundant reduce of the 64 partials (L2-hot) -> global max|w|
__device__ __forceinline__ float reduce_partials(const float* __restrict__ partials, int tid) {
    float p = partials[tid & 63];
    #pragma unroll
    for (int s = 32; s > 0; s >>= 1) p = fmaxf(p, __shfl_xor(p, s, 64));
    return p;
}

// ---------------- k2: quantize weights to int8 ----------------
__global__ void k_wquant(const float* __restrict__ w, const float* __restrict__ partials,
                         signed char* __restrict__ wq) {
    int idx = blockIdx.x * 256 + threadIdx.x;
    float scale = reduce_partials(partials, threadIdx.x) / 7.0f;  // scale_w (f32 div, as ref)
    float4 f = ((const float4*)w)[idx];
    int q0 = (int)rintf(fminf(fmaxf(f.x / scale, -7.f), 7.f));
    int q1 = (int)rintf(fminf(fmaxf(f.y / scale, -7.f), 7.f));
    int q2 = (int)rintf(fminf(fmaxf(f.z / scale, -7.f), 7.f));
    int q3 = (int)rintf(fminf(fmaxf(f.w / scale, -7.f), 7.f));
    ((int*)wq)[idx] = (q0 & 255) | ((q1 & 255) << 8) | ((q2 & 255) << 16) | ((q3 & 255) << 24);
}

// ---------------- k3: int8 MFMA GEMM + per-tile psum quant + stats ----------------
// 1024 blocks x 512 threads (8 waves), 64 batch rows/block. Each wave owns 32
// output channels (2 o-tiles) -> wf[2][4]=32 regs + f[8]=32 staging fits the
// __launch_bounds__(512,4) cap of 128 VGPRs. 2 blocks/CU -> 512 co-resident =
// exactly 2 full-width rounds (no straggler), 16 waves/CU latency hiding.
// No fences/tails: stats via plain relaxed atomicAdd; dispatch boundary orders.
template <typename ST>
__global__ __launch_bounds__(512, 4) void k_gemm(
    const float* __restrict__ x, const signed char* __restrict__ wq,
    ST* __restrict__ sbuf, int* __restrict__ stats)
{
    __shared__ __align__(16) signed char ldsx[64 * 272];   // 64 rows x 256 k (+16B pad/row)
    const int tid  = threadIdx.x;
    const int lane = tid & 63;
    const int wv   = tid >> 6;            // 0..7
    const int obase = wv * 32;            // 32 channels per wave
    const int lr = lane & 15, quad = lane >> 4;
    const size_t rb0 = (size_t)blockIdx.x * 64;

    // ---- issue all 64-row x loads (coalesced 8KB/inst; NT keeps L2 for sbuf/wq) ----
    v4f f[8];
    const v4f* xb = (const v4f*)(x + rb0 * 256);
    #pragma unroll
    for (int j = 0; j < 8; ++j)
        f[j] = __builtin_nontemporal_load(&xb[j * 512 + tid]);

    // ---- weight fragments (L2-hot): B-operand layout n=lane&15, k=quad*16+i ----
    v4i wf[2][4];
    #pragma unroll
    for (int ot = 0; ot < 2; ++ot)
        #pragma unroll
        for (int kt = 0; kt < 4; ++kt)
            wf[ot][kt] = *(const v4i*)(wq + (size_t)(obase + ot * 16 + lr) * 256 + kt * 64 + quad * 16);

    // ---- quantize acts to int8 -> LDS ----
    #pragma unroll
    for (int j = 0; j < 8; ++j) {
        int idx = j * 512 + tid;            // float4 flat index (0..4095)
        int row = idx >> 6, c = idx & 63;   // 64 float4 per row
        int b0 = (int)rintf(fminf(fmaxf(f[j][0], 0.f), 1.f) * 15.f);
        int b1 = (int)rintf(fminf(fmaxf(f[j][1], 0.f), 1.f) * 15.f);
        int b2 = (int)rintf(fminf(fmaxf(f[j][2], 0.f), 1.f) * 15.f);
        int b3 = (int)rintf(fminf(fmaxf(f[j][3], 0.f), 1.f) * 15.f);
        *(int*)(ldsx + row * 272 + c * 4) = b0 | (b1 << 8) | (b2 << 16) | (b3 << 24);
    }
    __syncthreads();   // the ONLY barrier

    int ssum[2] = {0, 0};
    int ssq[2]  = {0, 0};

    #pragma unroll
    for (int t = 0; t < 4; ++t) {
        // A fragments for row-tile t: m=lane&15, k=quad*16+i
        v4i a[4];
        #pragma unroll
        for (int kt = 0; kt < 4; ++kt)
            a[kt] = *(const v4i*)(ldsx + (t * 16 + lr) * 272 + kt * 64 + quad * 16);
        const size_t rowbase = rb0 + (size_t)t * 16;
        #pragma unroll
        for (int ot = 0; ot < 2; ++ot) {
            v4i acc0 = {0, 0, 0, 0}, acc1 = {0, 0, 0, 0};
            acc0 = __builtin_amdgcn_mfma_i32_16x16x64_i8(a[0], wf[ot][0], acc0, 0, 0, 0);
            acc0 = __builtin_amdgcn_mfma_i32_16x16x64_i8(a[1], wf[ot][1], acc0, 0, 0, 0);
            acc1 = __builtin_amdgcn_mfma_i32_16x16x64_i8(a[2], wf[ot][2], acc1, 0, 0, 0);
            acc1 = __builtin_amdgcn_mfma_i32_16x16x64_i8(a[3], wf[ot][3], acc1, 0, 0, 0);
            ST* sp = sbuf + (rowbase + quad * 4) * 256 + obase + ot * 16 + lr;
            #pragma unroll
            for (int e = 0; e < 4; ++e) {
                int s = rhe1792(acc0[e]) + rhe1792(acc1[e]);   // exact, in [-16,16]
                ssum[ot] += s;
                ssq[ot]  += s * s;
                sp[(size_t)e * 256] = (ST)s;
            }
        }
    }
    // ---- per-channel stats into replica buffer (plain relaxed device atomics) ----
    int* st = stats + (blockIdx.x & (NREP - 1)) * 512;
    #pragma unroll
    for (int ot = 0; ot < 2; ++ot) {
        int v = ssum[ot], u = ssq[ot];
        v += __shfl_xor(v, 16, 64); v += __shfl_xor(v, 32, 64);
        u += __shfl_xor(u, 16, 64); u += __shfl_xor(u, 32, 64);
        if (quad == 0) {
            atomicAdd(&st[obase + ot * 16 + lr], v);
            atomicAdd(&st[256 + obase + ot * 16 + lr], u);
        }
    }
}

// ---------------- k4: per-channel BN affine from exact integer stats ----------------
__global__ void k_stats(const int* __restrict__ stats, const float* __restrict__ partials,
                        const float* __restrict__ gamma, const float* __restrict__ beta,
                        float2* __restrict__ AB)
{
    int o = threadIdx.x;
    int s = 0, q = 0;
    #pragma unroll
    for (int rr = 0; rr < NREP; ++rr) {
        s += stats[rr * 512 + o];
        q += stats[rr * 512 + 256 + o];
    }
    float scale_w = reduce_partials(partials, o) / 7.0f;
    float t = scale_w / 15.0f;                 // ref: scale_w / qmax_a in f32
    double Cs = 1792.0 * (double)t;            // acc = s * Cs
    const double N = 65536.0;
    double mean_s = (double)s / N;
    double var_s  = (double)q / N - mean_s * mean_s;
    double var    = Cs * Cs * var_s;
    double inv    = 1.0 / sqrt(var + 1e-5);
    double A = Cs * inv * (double)gamma[o];
    double B = (double)beta[o] - Cs * mean_s * inv * (double)gamma[o];
    AB[o] = make_float2((float)A, (float)B);
}

// ---------------- k5: epilogue — BN affine + clipped-ReLU quant ----------------
// 4096 blocks x 256 threads; thread t handles 4-elem groups at flat int-index
// blk*1024 + j*256 + t: loads AND stores fully coalesced, no LDS.
template <typename LT>
__global__ __launch_bounds__(256) void k_out(const LT* sbuf, const float2* __restrict__ AB,
                                             float* out)
{
    const int tid = threadIdx.x;
    const int o0 = (tid * 4) & 255;
    const float4 ab01 = *(const float4*)((const float*)AB + 2 * o0);      // A0,B0,A1,B1
    const float4 ab23 = *(const float4*)((const float*)AB + 2 * o0 + 4);  // A2,B2,A3,B3
    const size_t base = (size_t)blockIdx.x * 1024 + tid;   // 4-element-group index
    #pragma unroll
    for (int j = 0; j < 4; ++j) {
        const size_t F4 = base + (size_t)j * 256;
        float v0, v1, v2, v3;
        if constexpr (sizeof(LT) == 1) {
            int sv = ((const int*)sbuf)[F4];
            v0 = (float)((sv << 24) >> 24);
            v1 = (float)((sv << 16) >> 24);
            v2 = (float)((sv << 8) >> 24);
            v3 = (float)(sv >> 24);
        } else {
            v4f fl = ((const v4f*)sbuf)[F4];
            v0 = fl[0]; v1 = fl[1]; v2 = fl[2]; v3 = fl[3];
        }
        float y0 = rintf(fminf(fmaxf(v0 * ab01.x + ab01.y, 0.f), 1.f) * 15.f);
        float y1 = rintf(fminf(fmaxf(v1 * ab01.z + ab01.w, 0.f), 1.f) * 15.f);
        float y2 = rintf(fminf(fmaxf(v2 * ab23.x + ab23.y, 0.f), 1.f) * 15.f);
        float y3 = rintf(fminf(fmaxf(v3 * ab23.z + ab23.w, 0.f), 1.f) * 15.f);
        const float inv15 = 0.066666666666666666f;
        v4f o = { y0 * inv15, y1 * inv15, y2 * inv15, y3 * inv15 };
        __builtin_nontemporal_store(o, (v4f*)out + F4);   // out never re-read
    }
}

// ---------------- launch ----------------
extern "C" void kernel_launch(void* const* d_in, const int* in_sizes, int n_in,
                              void* d_out, int out_size, void* d_ws, size_t ws_size,
                              hipStream_t stream)
{
    const float* x     = (const float*)d_in[0];
    const float* w     = (const float*)d_in[1];
    const float* gamma = (const float*)d_in[2];
    const float* beta  = (const float*)d_in[3];
    float* out = (float*)d_out;
    char* ws = (char*)d_ws;

    signed char* wq       = (signed char*)(ws + WQ_OFF);
    int*         stats    = (int*)(ws + STATS_OFF);
    float*       partials = (float*)(ws + PART_OFF);
    float2*      AB       = (float2*)(ws + AB_OFF);

    k_maxabs<<<dim3(64), dim3(256), 0, stream>>>(w, partials, stats);
    k_wquant<<<dim3(64), dim3(256), 0, stream>>>(w, partials, wq);

    if (ws_size >= WS_NEEDED) {
        signed char* sbuf = (signed char*)(ws + SBUF_OFF);
        k_gemm<signed char><<<dim3(1024), dim3(512), 0, stream>>>(x, wq, sbuf, stats);
        k_stats<<<dim3(1), dim3(256), 0, stream>>>(stats, partials, gamma, beta, AB);
        k_out<signed char><<<dim3(4096), dim3(256), 0, stream>>>(sbuf, AB, out);
    } else {
        // fallback: stage s as fp32 in d_out, finish in place (same-thread indices)
        k_gemm<float><<<dim3(1024), dim3(512), 0, stream>>>(x, wq, out, stats);
        k_stats<<<dim3(1), dim3(256), 0, stream>>>(stats, partials, gamma, beta, AB);
        k_out<float><<<dim3(4096), dim3(256), 0, stream>>>(out, AB, out);
    }
}

// Round 10
// 135.082 us; speedup vs baseline: 3.3300x; 1.0463x over previous
//
#include <hip/hip_runtime.h>
#include <cstdint>
#include <cstddef>

typedef int   v4i __attribute__((ext_vector_type(4)));
typedef float v4f __attribute__((ext_vector_type(4)));

static constexpr int NREP = 8;    // stats replica count (atomic contention spreading)

// ---------------- workspace layout (bytes) ----------------
static constexpr size_t WQ_OFF    = 0;                        // 65536 int8 weights
static constexpr size_t STATS_OFF = 65536;                    // NREP*512 int32 = 16384
static constexpr size_t PART_OFF  = STATS_OFF + NREP*512*4;   // 64 floats
static constexpr size_t SBUF_OFF  = 131072 + 2048;            // 16 MiB int8 s-values
static constexpr size_t WS_NEEDED = SBUF_OFF + (size_t)65536 * 256;

// exact round-half-even of p/1792 for |p| <= 13440 (1792 = 7*256)
__device__ __forceinline__ int rhe1792(int p) {
    unsigned u = (unsigned)(p + 17024);      // (p+896) + 9*1792, u in [3584,30464]
    unsigned v = u >> 8;                     // floor(u/256), in [14,119]
    unsigned d = (v * 147u) >> 10;           // floor(v/7), exact for v<=119
    int q = (int)d - 9;                      // round-half-up(p/1792)
    unsigned tie = (unsigned)(((u & 255u) | (v - 7u * d)) == 0u);
    q -= (int)(tie & ((unsigned)q & 1u));    // half-even: ties round to even
    return q;
}

// ---------------- k1: per-block max|w| partials + zero stats ----------------
__global__ void k_maxabs(const float* __restrict__ w, float* __restrict__ partials,
                         int* __restrict__ stats) {
    __shared__ float wmax[4];
    int idx = blockIdx.x * 256 + threadIdx.x;     // 64 blocks * 256 = 16384 float4
    float4 f = ((const float4*)w)[idx];
    float m = fmaxf(fmaxf(fabsf(f.x), fabsf(f.y)), fmaxf(fabsf(f.z), fabsf(f.w)));
    #pragma unroll
    for (int s = 32; s > 0; s >>= 1) m = fmaxf(m, __shfl_xor(m, s, 64));
    if ((threadIdx.x & 63) == 0) wmax[threadIdx.x >> 6] = m;
    if (idx < NREP * 512) stats[idx] = 0;         // zero replicas
    __syncthreads();
    if (threadIdx.x == 0)
        partials[blockIdx.x] = fmaxf(fmaxf(wmax[0], wmax[1]), fmaxf(wmax[2], wmax[3]));
}

// wave-redundant reduce of the 64 partials (L2-hot) -> global max|w|
__device__ __forceinline__ float reduce_partials(const float* __restrict__ partials, int tid) {
    float p = partials[tid & 63];
    #pragma unroll
    for (int s = 32; s > 0; s >>= 1) p = fmaxf(p, __shfl_xor(p, s, 64));
    return p;
}

// ---------------- k2: quantize weights to int8 ----------------
__global__ void k_wquant(const float* __restrict__ w, const float* __restrict__ partials,
                         signed char* __restrict__ wq) {
    int idx = blockIdx.x * 256 + threadIdx.x;
    float scale = reduce_partials(partials, threadIdx.x) / 7.0f;  // scale_w (f32 div, as ref)
    float4 f = ((const float4*)w)[idx];
    int q0 = (int)rintf(fminf(fmaxf(f.x / scale, -7.f), 7.f));
    int q1 = (int)rintf(fminf(fmaxf(f.y / scale, -7.f), 7.f));
    int q2 = (int)rintf(fminf(fmaxf(f.z / scale, -7.f), 7.f));
    int q3 = (int)rintf(fminf(fmaxf(f.w / scale, -7.f), 7.f));
    ((int*)wq)[idx] = (q0 & 255) | ((q1 & 255) << 8) | ((q2 & 255) << 16) | ((q3 & 255) << 24);
}

// ---------------- k3: int8 MFMA GEMM + per-tile psum quant + stats ----------------
// 1024 blocks x 512 threads (8 waves), 64 batch rows/block, wf[2][4] per wave,
// __launch_bounds__(512,4): 2 blocks/CU -> 512 co-resident = 2 full-width rounds.
// x loads are PLAIN (not NT): x is L3-warm from the harness restore; NT forced
// HBM-rate streaming. sbuf stores stay plain so k_out can hit them in L2/L3.
template <typename ST>
__global__ __launch_bounds__(512, 4) void k_gemm(
    const float* __restrict__ x, const signed char* __restrict__ wq,
    ST* __restrict__ sbuf, int* __restrict__ stats)
{
    __shared__ __align__(16) signed char ldsx[64 * 272];   // 64 rows x 256 k (+16B pad/row)
    const int tid  = threadIdx.x;
    const int lane = tid & 63;
    const int wv   = tid >> 6;            // 0..7
    const int obase = wv * 32;            // 32 channels per wave
    const int lr = lane & 15, quad = lane >> 4;
    const size_t rb0 = (size_t)blockIdx.x * 64;

    // ---- issue all 64-row x loads (coalesced 8KB/inst, L3-served) ----
    v4f f[8];
    const v4f* xb = (const v4f*)(x + rb0 * 256);
    #pragma unroll
    for (int j = 0; j < 8; ++j)
        f[j] = xb[j * 512 + tid];

    // ---- weight fragments (L2-hot): B-operand layout n=lane&15, k=quad*16+i ----
    v4i wf[2][4];
    #pragma unroll
    for (int ot = 0; ot < 2; ++ot)
        #pragma unroll
        for (int kt = 0; kt < 4; ++kt)
            wf[ot][kt] = *(const v4i*)(wq + (size_t)(obase + ot * 16 + lr) * 256 + kt * 64 + quad * 16);

    // ---- quantize acts to int8 -> LDS ----
    #pragma unroll
    for (int j = 0; j < 8; ++j) {
        int idx = j * 512 + tid;            // float4 flat index (0..4095)
        int row = idx >> 6, c = idx & 63;   // 64 float4 per row
        int b0 = (int)rintf(fminf(fmaxf(f[j][0], 0.f), 1.f) * 15.f);
        int b1 = (int)rintf(fminf(fmaxf(f[j][1], 0.f), 1.f) * 15.f);
        int b2 = (int)rintf(fminf(fmaxf(f[j][2], 0.f), 1.f) * 15.f);
        int b3 = (int)rintf(fminf(fmaxf(f[j][3], 0.f), 1.f) * 15.f);
        *(int*)(ldsx + row * 272 + c * 4) = b0 | (b1 << 8) | (b2 << 16) | (b3 << 24);
    }
    __syncthreads();   // the ONLY barrier

    int ssum[2] = {0, 0};
    int ssq[2]  = {0, 0};

    #pragma unroll
    for (int t = 0; t < 4; ++t) {
        v4i a[4];
        #pragma unroll
        for (int kt = 0; kt < 4; ++kt)
            a[kt] = *(const v4i*)(ldsx + (t * 16 + lr) * 272 + kt * 64 + quad * 16);
        const size_t rowbase = rb0 + (size_t)t * 16;
        #pragma unroll
        for (int ot = 0; ot < 2; ++ot) {
            v4i acc0 = {0, 0, 0, 0}, acc1 = {0, 0, 0, 0};
            acc0 = __builtin_amdgcn_mfma_i32_16x16x64_i8(a[0], wf[ot][0], acc0, 0, 0, 0);
            acc0 = __builtin_amdgcn_mfma_i32_16x16x64_i8(a[1], wf[ot][1], acc0, 0, 0, 0);
            acc1 = __builtin_amdgcn_mfma_i32_16x16x64_i8(a[2], wf[ot][2], acc1, 0, 0, 0);
            acc1 = __builtin_amdgcn_mfma_i32_16x16x64_i8(a[3], wf[ot][3], acc1, 0, 0, 0);
            ST* sp = sbuf + (rowbase + quad * 4) * 256 + obase + ot * 16 + lr;
            #pragma unroll
            for (int e = 0; e < 4; ++e) {
                int s = rhe1792(acc0[e]) + rhe1792(acc1[e]);   // exact, in [-16,16]
                ssum[ot] += s;
                ssq[ot]  += s * s;
                sp[(size_t)e * 256] = (ST)s;
            }
        }
    }
    // ---- per-channel stats into replica buffer (plain relaxed device atomics) ----
    int* st = stats + (blockIdx.x & (NREP - 1)) * 512;
    #pragma unroll
    for (int ot = 0; ot < 2; ++ot) {
        int v = ssum[ot], u = ssq[ot];
        v += __shfl_xor(v, 16, 64); v += __shfl_xor(v, 32, 64);
        u += __shfl_xor(u, 16, 64); u += __shfl_xor(u, 32, 64);
        if (quad == 0) {
            atomicAdd(&st[obase + ot * 16 + lr], v);
            atomicAdd(&st[256 + obase + ot * 16 + lr], u);
        }
    }
}

// ---------------- k4: epilogue — BN affine (computed in-block) + clipped-ReLU ----
// 4096 blocks x 256 threads. Each block first computes the 256-channel BN affine
// redundantly from the exact integer stats (16 coalesced L2-hot loads + one double
// rsqrt per thread; bit-identical op order to the old k_stats), shares it in LDS,
// then runs the coalesced epilogue. Block-index swizzle d makes (d>>2)%8 == b%8 so
// each block reads the sbuf rows written on its own XCD (L2-local).
template <typename LT>
__global__ __launch_bounds__(256) void k_out(const LT* sbuf, const int* __restrict__ stats,
                                             const float* __restrict__ partials,
                                             const float* __restrict__ gamma,
                                             const float* __restrict__ beta,
                                             float* out)
{
    __shared__ float2 ab[256];
    const int tid = threadIdx.x;
    {
        int o = tid;
        int s = 0, q = 0;
        #pragma unroll
        for (int rr = 0; rr < NREP; ++rr) {
            s += stats[rr * 512 + o];
            q += stats[rr * 512 + 256 + o];
        }
        float scale_w = reduce_partials(partials, o) / 7.0f;
        float t = scale_w / 15.0f;                 // ref: scale_w / qmax_a in f32
        double Cs = 1792.0 * (double)t;            // acc = s * Cs
        const double N = 65536.0;
        double mean_s = (double)s / N;
        double var_s  = (double)q / N - mean_s * mean_s;
        double var    = Cs * Cs * var_s;
        double inv    = 1.0 / sqrt(var + 1e-5);
        double A = Cs * inv * (double)gamma[o];
        double B = (double)beta[o] - Cs * mean_s * inv * (double)gamma[o];
        ab[o] = make_float2((float)A, (float)B);
    }
    __syncthreads();

    const int b = blockIdx.x;
    const int d = ((b & 7) << 2) | ((b >> 3) & 3) | (b & ~31);   // XCD-aligned bijection
    const int o0 = (tid * 4) & 255;
    const float2 p0 = ab[o0], p1 = ab[o0 + 1], p2 = ab[o0 + 2], p3 = ab[o0 + 3];
    const size_t base = (size_t)d * 1024 + tid;   // 4-element-group index
    #pragma unroll
    for (int j = 0; j < 4; ++j) {
        const size_t F4 = base + (size_t)j * 256;
        float v0, v1, v2, v3;
        if constexpr (sizeof(LT) == 1) {
            int sv = ((const int*)sbuf)[F4];
            v0 = (float)((sv << 24) >> 24);
            v1 = (float)((sv << 16) >> 24);
            v2 = (float)((sv << 8) >> 24);
            v3 = (float)(sv >> 24);
        } else {
            v4f fl = ((const v4f*)sbuf)[F4];
            v0 = fl[0]; v1 = fl[1]; v2 = fl[2]; v3 = fl[3];
        }
        float y0 = rintf(fminf(fmaxf(v0 * p0.x + p0.y, 0.f), 1.f) * 15.f);
        float y1 = rintf(fminf(fmaxf(v1 * p1.x + p1.y, 0.f), 1.f) * 15.f);
        float y2 = rintf(fminf(fmaxf(v2 * p2.x + p2.y, 0.f), 1.f) * 15.f);
        float y3 = rintf(fminf(fmaxf(v3 * p3.x + p3.y, 0.f), 1.f) * 15.f);
        const float inv15 = 0.066666666666666666f;
        v4f o = { y0 * inv15, y1 * inv15, y2 * inv15, y3 * inv15 };
        __builtin_nontemporal_store(o, (v4f*)out + F4);   // out never re-read
    }
}

// ---------------- launch ----------------
extern "C" void kernel_launch(void* const* d_in, const int* in_sizes, int n_in,
                              void* d_out, int out_size, void* d_ws, size_t ws_size,
                              hipStream_t stream)
{
    const float* x     = (const float*)d_in[0];
    const float* w     = (const float*)d_in[1];
    const float* gamma = (const float*)d_in[2];
    const float* beta  = (const float*)d_in[3];
    float* out = (float*)d_out;
    char* ws = (char*)d_ws;

    signed char* wq       = (signed char*)(ws + WQ_OFF);
    int*         stats    = (int*)(ws + STATS_OFF);
    float*       partials = (float*)(ws + PART_OFF);

    k_maxabs<<<dim3(64), dim3(256), 0, stream>>>(w, partials, stats);
    k_wquant<<<dim3(64), dim3(256), 0, stream>>>(w, partials, wq);

    if (ws_size >= WS_NEEDED) {
        signed char* sbuf = (signed char*)(ws + SBUF_OFF);
        k_gemm<signed char><<<dim3(1024), dim3(512), 0, stream>>>(x, wq, sbuf, stats);
        k_out<signed char><<<dim3(4096), dim3(256), 0, stream>>>(sbuf, stats, partials,
                                                                 gamma, beta, out);
    } else {
        // fallback: stage s as fp32 in d_out, finish in place (same-thread indices)
        k_gemm<float><<<dim3(1024), dim3(512), 0, stream>>>(x, wq, out, stats);
        k_out<float><<<dim3(4096), dim3(256), 0, stream>>>(out, stats, partials,
                                                           gamma, beta, out);
    }
}

// Round 11
// 131.817 us; speedup vs baseline: 3.4125x; 1.0248x over previous
//
#include <hip/hip_runtime.h>
#include <cstdint>
#include <cstddef>

typedef int   v4i __attribute__((ext_vector_type(4)));
typedef float v4f __attribute__((ext_vector_type(4)));

static constexpr int NREP = 8;    // stats replica count (atomic contention spreading)

// ---------------- workspace layout (bytes) ----------------
static constexpr size_t WQ_OFF    = 0;                        // 65536 int8 weights
static constexpr size_t STATS_OFF = 65536;                    // NREP*512 int32 = 16384
static constexpr size_t PART_OFF  = STATS_OFF + NREP*512*4;   // 64 floats
static constexpr size_t SBUF_OFF  = 131072 + 2048;            // 16 MiB s-values (dword grid)
static constexpr size_t WS_NEEDED = SBUF_OFF + (size_t)65536 * 256;

// exact round-half-even of p/1792 for |p| <= 13440 (1792 = 7*256)
__device__ __forceinline__ int rhe1792(int p) {
    unsigned u = (unsigned)(p + 17024);      // (p+896) + 9*1792, u in [3584,30464]
    unsigned v = u >> 8;                     // floor(u/256), in [14,119]
    unsigned d = (v * 147u) >> 10;           // floor(v/7), exact for v<=119
    int q = (int)d - 9;                      // round-half-up(p/1792)
    unsigned tie = (unsigned)(((u & 255u) | (v - 7u * d)) == 0u);
    q -= (int)(tie & ((unsigned)q & 1u));    // half-even: ties round to even
    return q;
}

// ---------------- k1: per-block max|w| partials + zero stats ----------------
__global__ void k_maxabs(const float* __restrict__ w, float* __restrict__ partials,
                         int* __restrict__ stats) {
    __shared__ float wmax[4];
    int idx = blockIdx.x * 256 + threadIdx.x;     // 64 blocks * 256 = 16384 float4
    float4 f = ((const float4*)w)[idx];
    float m = fmaxf(fmaxf(fabsf(f.x), fabsf(f.y)), fmaxf(fabsf(f.z), fabsf(f.w)));
    #pragma unroll
    for (int s = 32; s > 0; s >>= 1) m = fmaxf(m, __shfl_xor(m, s, 64));
    if ((threadIdx.x & 63) == 0) wmax[threadIdx.x >> 6] = m;
    if (idx < NREP * 512) stats[idx] = 0;         // zero replicas
    __syncthreads();
    if (threadIdx.x == 0)
        partials[blockIdx.x] = fmaxf(fmaxf(wmax[0], wmax[1]), fmaxf(wmax[2], wmax[3]));
}

// wave-redundant reduce of the 64 partials (L2-hot) -> global max|w|
__device__ __forceinline__ float reduce_partials(const float* __restrict__ partials, int tid) {
    float p = partials[tid & 63];
    #pragma unroll
    for (int s = 32; s > 0; s >>= 1) p = fmaxf(p, __shfl_xor(p, s, 64));
    return p;
}

// ---------------- k2: quantize weights to int8 ----------------
__global__ void k_wquant(const float* __restrict__ w, const float* __restrict__ partials,
                         signed char* __restrict__ wq) {
    int idx = blockIdx.x * 256 + threadIdx.x;
    float scale = reduce_partials(partials, threadIdx.x) / 7.0f;  // scale_w (f32 div, as ref)
    float4 f = ((const float4*)w)[idx];
    int q0 = (int)rintf(fminf(fmaxf(f.x / scale, -7.f), 7.f));
    int q1 = (int)rintf(fminf(fmaxf(f.y / scale, -7.f), 7.f));
    int q2 = (int)rintf(fminf(fmaxf(f.z / scale, -7.f), 7.f));
    int q3 = (int)rintf(fminf(fmaxf(f.w / scale, -7.f), 7.f));
    ((int*)wq)[idx] = (q0 & 255) | ((q1 & 255) << 8) | ((q2 & 255) << 16) | ((q3 & 255) << 24);
}

// ---------------- k3: int8 MFMA GEMM + per-tile psum quant + stats ----------------
// 1024 blocks x 512 threads (8 waves), 64 batch rows/block, wf[2][4] per wave,
// __launch_bounds__(512,4): 2 blocks/CU -> 512 co-resident = 2 full-width rounds.
// ST=signed char: s stored as a DWORD GRID sbuf[rowgroup][col] (byte e of dword =
// row 4*rg+e) exploiting the C-layout (acc regs e=0..3 are 4 consecutive rows,
// same col) -> one dword store replaces 4 scattered byte stores.
template <typename ST>
__global__ __launch_bounds__(512, 4) void k_gemm(
    const float* __restrict__ x, const signed char* __restrict__ wq,
    ST* __restrict__ sbuf, int* __restrict__ stats)
{
    __shared__ __align__(16) signed char ldsx[64 * 272];   // 64 rows x 256 k (+16B pad/row)
    const int tid  = threadIdx.x;
    const int lane = tid & 63;
    const int wv   = tid >> 6;            // 0..7
    const int obase = wv * 32;            // 32 channels per wave
    const int lr = lane & 15, quad = lane >> 4;
    const size_t rb0 = (size_t)blockIdx.x * 64;

    // ---- issue all 64-row x loads (coalesced 8KB/inst, L3-served) ----
    v4f f[8];
    const v4f* xb = (const v4f*)(x + rb0 * 256);
    #pragma unroll
    for (int j = 0; j < 8; ++j)
        f[j] = xb[j * 512 + tid];

    // ---- weight fragments (L2-hot): B-operand layout n=lane&15, k=quad*16+i ----
    v4i wf[2][4];
    #pragma unroll
    for (int ot = 0; ot < 2; ++ot)
        #pragma unroll
        for (int kt = 0; kt < 4; ++kt)
            wf[ot][kt] = *(const v4i*)(wq + (size_t)(obase + ot * 16 + lr) * 256 + kt * 64 + quad * 16);

    // ---- quantize acts to int8 -> LDS ----
    #pragma unroll
    for (int j = 0; j < 8; ++j) {
        int idx = j * 512 + tid;            // float4 flat index (0..4095)
        int row = idx >> 6, c = idx & 63;   // 64 float4 per row
        int b0 = (int)rintf(fminf(fmaxf(f[j][0], 0.f), 1.f) * 15.f);
        int b1 = (int)rintf(fminf(fmaxf(f[j][1], 0.f), 1.f) * 15.f);
        int b2 = (int)rintf(fminf(fmaxf(f[j][2], 0.f), 1.f) * 15.f);
        int b3 = (int)rintf(fminf(fmaxf(f[j][3], 0.f), 1.f) * 15.f);
        *(int*)(ldsx + row * 272 + c * 4) = b0 | (b1 << 8) | (b2 << 16) | (b3 << 24);
    }
    __syncthreads();   // the ONLY barrier

    int ssum[2] = {0, 0};
    int ssq[2]  = {0, 0};

    #pragma unroll
    for (int t = 0; t < 4; ++t) {
        v4i a[4];
        #pragma unroll
        for (int kt = 0; kt < 4; ++kt)
            a[kt] = *(const v4i*)(ldsx + (t * 16 + lr) * 272 + kt * 64 + quad * 16);
        #pragma unroll
        for (int ot = 0; ot < 2; ++ot) {
            v4i acc0 = {0, 0, 0, 0}, acc1 = {0, 0, 0, 0};
            acc0 = __builtin_amdgcn_mfma_i32_16x16x64_i8(a[0], wf[ot][0], acc0, 0, 0, 0);
            acc0 = __builtin_amdgcn_mfma_i32_16x16x64_i8(a[1], wf[ot][1], acc0, 0, 0, 0);
            acc1 = __builtin_amdgcn_mfma_i32_16x16x64_i8(a[2], wf[ot][2], acc1, 0, 0, 0);
            acc1 = __builtin_amdgcn_mfma_i32_16x16x64_i8(a[3], wf[ot][3], acc1, 0, 0, 0);
            const int ocol = obase + ot * 16 + lr;
            if constexpr (sizeof(ST) == 1) {
                // vertical pack: byte e = row quad*4+e (rowgroup rg), col ocol
                unsigned pack = 0;
                #pragma unroll
                for (int e = 0; e < 4; ++e) {
                    int s = rhe1792(acc0[e]) + rhe1792(acc1[e]);   // exact, in [-16,16]
                    ssum[ot] += s;
                    ssq[ot]  += s * s;
                    pack |= (unsigned)(s & 255) << (8 * e);
                }
                const size_t rg = (size_t)blockIdx.x * 16 + t * 4 + quad;
                ((unsigned*)sbuf)[rg * 256 + ocol] = pack;
            } else {
                ST* sp = sbuf + (rb0 + (size_t)t * 16 + quad * 4) * 256 + ocol;
                #pragma unroll
                for (int e = 0; e < 4; ++e) {
                    int s = rhe1792(acc0[e]) + rhe1792(acc1[e]);
                    ssum[ot] += s;
                    ssq[ot]  += s * s;
                    sp[(size_t)e * 256] = (ST)s;
                }
            }
        }
    }
    // ---- per-channel stats into replica buffer (plain relaxed device atomics) ----
    int* st = stats + (blockIdx.x & (NREP - 1)) * 512;
    #pragma unroll
    for (int ot = 0; ot < 2; ++ot) {
        int v = ssum[ot], u = ssq[ot];
        v += __shfl_xor(v, 16, 64); v += __shfl_xor(v, 32, 64);
        u += __shfl_xor(u, 16, 64); u += __shfl_xor(u, 32, 64);
        if (quad == 0) {
            atomicAdd(&st[obase + ot * 16 + lr], v);
            atomicAdd(&st[256 + obase + ot * 16 + lr], u);
        }
    }
}

// ---------------- k4: epilogue — BN affine (computed in-block) + clipped-ReLU ----
// 4096 blocks x 256 threads. Per-block redundant BN-affine from exact integer
// stats (bit-identical op order), then: thread t reads ONE dwordx4 (16 B contig,
// 1 KB/wave) = cols 4(t&63)..+3 of rowgroup 4d+(t>>6); extracts 16 signed bytes;
// writes 4 fully-coalesced float4 row segments (1 KB/wave each). Swizzle d keeps
// (d>>2)%8 == b%8 so reads hit the writer XCD's L2.
template <typename LT>
__global__ __launch_bounds__(256) void k_out(const LT* sbuf, const int* __restrict__ stats,
                                             const float* __restrict__ partials,
                                             const float* __restrict__ gamma,
                                             const float* __restrict__ beta,
                                             float* out)
{
    __shared__ float2 ab[256];
    const int tid = threadIdx.x;
    {
        int o = tid;
        int s = 0, q = 0;
        #pragma unroll
        for (int rr = 0; rr < NREP; ++rr) {
            s += stats[rr * 512 + o];
            q += stats[rr * 512 + 256 + o];
        }
        float scale_w = reduce_partials(partials, o) / 7.0f;
        float t = scale_w / 15.0f;                 // ref: scale_w / qmax_a in f32
        double Cs = 1792.0 * (double)t;            // acc = s * Cs
        const double N = 65536.0;
        double mean_s = (double)s / N;
        double var_s  = (double)q / N - mean_s * mean_s;
        double var    = Cs * Cs * var_s;
        double inv    = 1.0 / sqrt(var + 1e-5);
        double A = Cs * inv * (double)gamma[o];
        double B = (double)beta[o] - Cs * mean_s * inv * (double)gamma[o];
        ab[o] = make_float2((float)A, (float)B);
    }
    __syncthreads();

    const int b = blockIdx.x;
    const int d = ((b & 7) << 2) | ((b >> 3) & 3) | (b & ~31);   // XCD-aligned bijection
    const int ci = tid & 63;           // colgroup index (4 cols)
    const int c0 = ci * 4;
    const float2 p0 = ab[c0], p1 = ab[c0 + 1], p2 = ab[c0 + 2], p3 = ab[c0 + 3];
    const float inv15 = 0.066666666666666666f;

    if constexpr (sizeof(LT) == 1) {
        const int rg = d * 4 + (tid >> 6);         // global rowgroup (4 rows)
        v4i V = ((const v4i*)sbuf)[(size_t)rg * 64 + ci];   // cols c0..c0+3, rows 4rg..4rg+3
        #pragma unroll
        for (int j = 0; j < 4; ++j) {
            float v0 = (float)((V[0] << (24 - 8 * j)) >> 24);
            float v1 = (float)((V[1] << (24 - 8 * j)) >> 24);
            float v2 = (float)((V[2] << (24 - 8 * j)) >> 24);
            float v3 = (float)((V[3] << (24 - 8 * j)) >> 24);
            float y0 = rintf(fminf(fmaxf(v0 * p0.x + p0.y, 0.f), 1.f) * 15.f);
            float y1 = rintf(fminf(fmaxf(v1 * p1.x + p1.y, 0.f), 1.f) * 15.f);
            float y2 = rintf(fminf(fmaxf(v2 * p2.x + p2.y, 0.f), 1.f) * 15.f);
            float y3 = rintf(fminf(fmaxf(v3 * p3.x + p3.y, 0.f), 1.f) * 15.f);
            v4f o = { y0 * inv15, y1 * inv15, y2 * inv15, y3 * inv15 };
            __builtin_nontemporal_store(o, (v4f*)out + (size_t)(4 * rg + j) * 64 + ci);
        }
    } else {
        // fallback: fp32 s row-major in d_out, finish in place (same-thread indices)
        const size_t base = (size_t)d * 1024 + tid;
        #pragma unroll
        for (int j = 0; j < 4; ++j) {
            const size_t F4 = base + (size_t)j * 256;
            v4f fl = ((const v4f*)sbuf)[F4];
            const int oo = (tid * 4) & 255;
            float2 q0 = ab[oo], q1 = ab[oo + 1], q2 = ab[oo + 2], q3 = ab[oo + 3];
            float y0 = rintf(fminf(fmaxf(fl[0] * q0.x + q0.y, 0.f), 1.f) * 15.f);
            float y1 = rintf(fminf(fmaxf(fl[1] * q1.x + q1.y, 0.f), 1.f) * 15.f);
            float y2 = rintf(fminf(fmaxf(fl[2] * q2.x + q2.y, 0.f), 1.f) * 15.f);
            float y3 = rintf(fminf(fmaxf(fl[3] * q3.x + q3.y, 0.f), 1.f) * 15.f);
            v4f o = { y0 * inv15, y1 * inv15, y2 * inv15, y3 * inv15 };
            __builtin_nontemporal_store(o, (v4f*)out + F4);
        }
    }
}

// ---------------- launch ----------------
extern "C" void kernel_launch(void* const* d_in, const int* in_sizes, int n_in,
                              void* d_out, int out_size, void* d_ws, size_t ws_size,
                              hipStream_t stream)
{
    const float* x     = (const float*)d_in[0];
    const float* w     = (const float*)d_in[1];
    const float* gamma = (const float*)d_in[2];
    const float* beta  = (const float*)d_in[3];
    float* out = (float*)d_out;
    char* ws = (char*)d_ws;

    signed char* wq       = (signed char*)(ws + WQ_OFF);
    int*         stats    = (int*)(ws + STATS_OFF);
    float*       partials = (float*)(ws + PART_OFF);

    k_maxabs<<<dim3(64), dim3(256), 0, stream>>>(w, partials, stats);
    k_wquant<<<dim3(64), dim3(256), 0, stream>>>(w, partials, wq);

    if (ws_size >= WS_NEEDED) {
        signed char* sbuf = (signed char*)(ws + SBUF_OFF);
        k_gemm<signed char><<<dim3(1024), dim3(512), 0, stream>>>(x, wq, sbuf, stats);
        k_out<signed char><<<dim3(4096), dim3(256), 0, stream>>>(sbuf, stats, partials,
                                                                 gamma, beta, out);
    } else {
        // fallback: stage s as fp32 in d_out, finish in place (same-thread indices)
        k_gemm<float><<<dim3(1024), dim3(512), 0, stream>>>(x, wq, out, stats);
        k_out<float><<<dim3(4096), dim3(256), 0, stream>>>(out, stats, partials,
                                                           gamma, beta, out);
    }
}